// Round 5
// baseline (248.818 us; speedup 1.0000x reference)
//
#include <hip/hip_runtime.h>
#include <math.h>

#define NBATCH 2
#define KBOX   512
#define CCH    256
#define NBIN   49                 // 7x7 bins
#define NCH    8                  // channels per block
#define BPB    (CCH/NCH)          // 32 blocks per box
#define COUT   (CCH*NBIN)         // 12544 outputs per box
#define WCAP   1152               // window floats per channel (worst case ~1060)

__global__ __launch_bounds__(256, 4) void roi_align_kernel(
    const float* __restrict__ f2, const float* __restrict__ f3,
    const float* __restrict__ f4, const float* __restrict__ f5,
    const float* __restrict__ boxes, float* __restrict__ out)
{
    const int bid  = blockIdx.x;
    const int m    = bid >> 5;        // box index (BPB == 32)
    const int cg   = bid & 31;        // channel group within box
    const int tid  = threadIdx.x;
    const int lane = tid & 63;
    const int wid  = tid >> 6;
    const int b    = m / KBOX;        // batch index

    __shared__ float win[NCH * WCAP];

    // ---- box, level selection (uniform across block) ----
    const float x1 = boxes[m*4+0];
    const float y1 = boxes[m*4+1];
    const float x2 = boxes[m*4+2];
    const float y2 = boxes[m*4+3];

    const float area = (x2 - x1) * (y2 - y1);
    const float size = sqrtf(area);
    float lvlf = floorf(4.0f + log2f(size / 224.0f + 1e-8f));
    lvlf = fminf(fmaxf(lvlf, 2.0f), 5.0f);
    const int lvl = (int)lvlf - 2;    // 0..3

    const int   H     = 256 >> lvl;   // square feature maps
    const int   HH    = H * H;
    const float scale = 0.25f / (float)(1 << lvl);
    const float Hf    = (float)H;

    const float* fptr = (lvl == 0) ? f2 : (lvl == 1) ? f3 : (lvl == 2) ? f4 : f5;
    const int c0 = cg * NCH;
    const float* plane0 = fptr + ((size_t)b * CCH + c0) * HH;

    // aligned=True: subtract 0.5 after scaling
    const float bx1 = x1 * scale - 0.5f;
    const float by1 = y1 * scale - 0.5f;
    const float bin_w = (x2 * scale - 0.5f - bx1) / 7.0f;
    const float bin_h = (y2 * scale - 0.5f - by1) / 7.0f;

    // ---- ROI window bounds (same clamp math as the taps -> taps are inside) ----
    // sample coords: g in {0.25 .. 6.75}, monotone since bin_w,bin_h >= 0
    const float sx_min = bx1 + 0.25f * bin_w;
    const float sx_max = bx1 + 6.75f * bin_w;
    const float sy_min = by1 + 0.25f * bin_h;
    const float sy_max = by1 + 6.75f * bin_h;
    const int wx0 = min((int)floorf(fmaxf(sx_min, 0.0f)), H - 1);
    const int wy0 = min((int)floorf(fmaxf(sy_min, 0.0f)), H - 1);
    const int wx1 = min(min((int)floorf(fmaxf(sx_max, 0.0f)), H - 1) + 1, H - 1);
    const int wy1 = min(min((int)floorf(fmaxf(sy_max, 0.0f)), H - 1) + 1, H - 1);
    const int wspan = wx1 - wx0 + 1;
    const int hspan = wy1 - wy0 + 1;
    const int wsz   = wspan * hspan;  // <= ~1060 by FPN level-assignment bound

    // ---- stage: coalesced row-major copy of each channel's window into LDS ----
    #pragma unroll 1
    for (int c = 0; c < NCH; ++c) {
        const float* src = plane0 + (size_t)c * HH + wy0 * H + wx0;
        float* dst = win + c * WCAP;
        for (int i = tid; i < wsz; i += 256) {
            const int r   = i / wspan;          // fast f32-rcp division
            const int col = i - r * wspan;
            dst[i] = src[r * H + col];
        }
    }

    // ---- per-lane bin taps, in window coordinates, kept in registers ----
    const int bin = (lane < 49) ? lane : 48;
    const int py  = bin / 7;
    const int px  = bin - py * 7;

    int   o[16];
    float w[16];
    #pragma unroll
    for (int s = 0; s < 4; ++s) {
        const int iy = s >> 1;
        const int ix = s & 1;
        const float gy = ((float)(2*py + iy) + 0.5f) * 0.5f;
        const float gx = ((float)(2*px + ix) + 0.5f) * 0.5f;
        const float yy = by1 + gy * bin_h;
        const float xx = bx1 + gx * bin_w;

        const bool valid = (yy >= -1.0f) && (yy <= Hf) && (xx >= -1.0f) && (xx <= Hf);

        const float yc = fmaxf(yy, 0.0f);
        const float xc = fmaxf(xx, 0.0f);
        int yl = min((int)floorf(yc), H - 1);
        int xl = min((int)floorf(xc), H - 1);
        const int yh = min(yl + 1, H - 1);
        const int xh = min(xl + 1, H - 1);
        const float fy = yc - (float)yl;
        const float fx = xc - (float)xl;

        const float vm = valid ? 0.25f : 0.0f;   // fold 2x2 mean into weights
        w[s*4+0] = (1.0f - fy) * (1.0f - fx) * vm;
        w[s*4+1] = (1.0f - fy) * fx          * vm;
        w[s*4+2] = fy          * (1.0f - fx) * vm;
        w[s*4+3] = fy          * fx          * vm;

        const int ry_l = (yl - wy0) * wspan;
        const int ry_h = (yh - wy0) * wspan;
        const int cx_l = xl - wx0;
        const int cx_h = xh - wx0;
        o[s*4+0] = ry_l + cx_l;
        o[s*4+1] = ry_l + cx_h;
        o[s*4+2] = ry_h + cx_l;
        o[s*4+3] = ry_h + cx_h;
    }

    __syncthreads();

    // ---- compute: each wave owns 2 channels; 32 ds_reads + 32 FMAs + 2 stores ----
    const float* w0 = win + (wid * 2    ) * WCAP;
    const float* w1 = win + (wid * 2 + 1) * WCAP;

    float v0[16], v1[16];
    #pragma unroll
    for (int t = 0; t < 16; ++t) v0[t] = w0[o[t]];
    #pragma unroll
    for (int t = 0; t < 16; ++t) v1[t] = w1[o[t]];

    float acc0 = 0.0f, acc1 = 0.0f;
    #pragma unroll
    for (int t = 0; t < 16; ++t) {
        acc0 += w[t] * v0[t];
        acc1 += w[t] * v1[t];
    }

    if (lane < 49) {
        float* outp = out + (size_t)m * COUT + (size_t)(c0 + wid * 2) * NBIN + lane;
        __builtin_nontemporal_store(acc0, outp);
        __builtin_nontemporal_store(acc1, outp + NBIN);
    }
}

extern "C" void kernel_launch(void* const* d_in, const int* in_sizes, int n_in,
                              void* d_out, int out_size, void* d_ws, size_t ws_size,
                              hipStream_t stream) {
    const float* f2    = (const float*)d_in[0];
    const float* f3    = (const float*)d_in[1];
    const float* f4    = (const float*)d_in[2];
    const float* f5    = (const float*)d_in[3];
    const float* boxes = (const float*)d_in[4];
    float* outp = (float*)d_out;

    dim3 grid(NBATCH * KBOX * BPB);   // 32768 blocks: one box x 8 channels each
    dim3 block(256);
    roi_align_kernel<<<grid, block, 0, stream>>>(f2, f3, f4, f5, boxes, outp);
}

// Round 6
// 105.069 us; speedup vs baseline: 2.3681x; 2.3681x over previous
//
#include <hip/hip_runtime.h>
#include <math.h>
#include <stdint.h>

#define NBATCH 2
#define KBOX   512
#define CCH    256
#define NBIN   49                 // 7x7 bins
#define NCH    8                  // channels per block
#define BPB    (CCH/NCH)          // 32 blocks per box
#define COUT   (CCH*NBIN)         // 12544 outputs per box
#define WCAP   1152               // per-channel window capacity (floats); proven max ~1060

typedef const uint32_t __attribute__((address_space(1)))* gas_u32p;
typedef uint32_t       __attribute__((address_space(3)))* las_u32p;

__global__ __launch_bounds__(256, 4) void roi_align_kernel(
    const float* __restrict__ f2, const float* __restrict__ f3,
    const float* __restrict__ f4, const float* __restrict__ f5,
    const float* __restrict__ boxes, float* __restrict__ out)
{
    const int bid  = blockIdx.x;
    const int m    = bid >> 5;        // box index (BPB == 32)
    const int cg   = bid & 31;        // channel group within box
    const int tid  = threadIdx.x;
    const int lane = tid & 63;
    const int wid  = tid >> 6;
    const int b    = m / KBOX;        // batch index

    __shared__ float win[NCH * WCAP];

    // ---- box, level selection (uniform across block) ----
    const float x1 = boxes[m*4+0];
    const float y1 = boxes[m*4+1];
    const float x2 = boxes[m*4+2];
    const float y2 = boxes[m*4+3];

    const float area = (x2 - x1) * (y2 - y1);
    const float size = sqrtf(area);
    float lvlf = floorf(4.0f + log2f(size / 224.0f + 1e-8f));
    lvlf = fminf(fmaxf(lvlf, 2.0f), 5.0f);
    const int lvl = (int)lvlf - 2;    // 0..3

    const int   H     = 256 >> lvl;   // square feature maps
    const int   HH    = H * H;
    const float scale = 0.25f / (float)(1 << lvl);
    const float Hf    = (float)H;

    const float* fptr = (lvl == 0) ? f2 : (lvl == 1) ? f3 : (lvl == 2) ? f4 : f5;
    const int c0 = cg * NCH;
    const float* plane0 = fptr + ((size_t)b * CCH + c0) * HH;

    // aligned=True: subtract 0.5 after scaling
    const float bx1 = x1 * scale - 0.5f;
    const float by1 = y1 * scale - 0.5f;
    const float bin_w = (x2 * scale - 0.5f - bx1) / 7.0f;
    const float bin_h = (y2 * scale - 0.5f - by1) / 7.0f;

    // ---- ROI window bounds (same clamp math as the taps -> taps inside) ----
    const float sx_min = bx1 + 0.25f * bin_w;
    const float sx_max = bx1 + 6.75f * bin_w;
    const float sy_min = by1 + 0.25f * bin_h;
    const float sy_max = by1 + 6.75f * bin_h;
    const int wx0 = min((int)floorf(fmaxf(sx_min, 0.0f)), H - 1);
    const int wy0 = min((int)floorf(fmaxf(sy_min, 0.0f)), H - 1);
    const int wx1 = min(min((int)floorf(fmaxf(sx_max, 0.0f)), H - 1) + 1, H - 1);
    const int wy1 = min(min((int)floorf(fmaxf(sy_max, 0.0f)), H - 1) + 1, H - 1);
    const int wspan = wx1 - wx0 + 1;
    const int hspan = wy1 - wy0 + 1;
    const int wsz   = wspan * hspan;  // <= ~1060 by FPN level-assignment bound

    // ---- stage: one (r,col) decode per element, 8 channels amortized,
    //      direct HBM->LDS (no VGPR round-trip, no ds_write) ----
    const float* src0 = plane0 + wy0 * H + wx0;
    for (int i = tid; i < wsz; i += 256) {
        const int r   = i / wspan;
        const int col = i - r * wspan;
        const float* sp = src0 + r * H + col;
        const int ldsbase = i & ~63;          // uniform per wave (lane = i & 63)
        #pragma unroll
        for (int c = 0; c < NCH; ++c) {
            __builtin_amdgcn_global_load_lds(
                (gas_u32p)(const void*)(sp + (size_t)c * HH),
                (las_u32p)(void*)(&win[c * WCAP + ldsbase]),
                4, 0, 0);
        }
    }
    // sentinel: the single one-past-end element a clamped x-hi pair-read can touch
    if (tid < NCH) win[tid * WCAP + wsz] = 0.0f;

    // ---- per-lane taps in registers: 8 rows of adjacent x-pairs ----
    const int bin = (lane < 49) ? lane : 48;
    const int py  = bin / 7;
    const int px  = bin - py * 7;

    int   o8 [8];
    float wlo[8];
    float whi[8];
    #pragma unroll
    for (int s = 0; s < 4; ++s) {
        const int iy = s >> 1;
        const int ix = s & 1;
        const float gy = ((float)(2*py + iy) + 0.5f) * 0.5f;
        const float gx = ((float)(2*px + ix) + 0.5f) * 0.5f;
        const float yy = by1 + gy * bin_h;
        const float xx = bx1 + gx * bin_w;

        const bool valid = (yy >= -1.0f) && (yy <= Hf) && (xx >= -1.0f) && (xx <= Hf);

        const float yc = fmaxf(yy, 0.0f);
        const float xc = fmaxf(xx, 0.0f);
        int yl = min((int)floorf(yc), H - 1);
        int xl = min((int)floorf(xc), H - 1);
        const int yh = min(yl + 1, H - 1);
        const int xh = min(xl + 1, H - 1);
        const float fy = yc - (float)yl;
        float fx = xc - (float)xl;
        if (xh == xl) fx = 0.0f;   // clamped pair: lo gets full weight, hi*0 (exact)

        const float vm  = valid ? 0.25f : 0.0f;   // fold 2x2 mean into weights
        const float wyl = (1.0f - fy) * vm;
        const float wyh = fy * vm;

        const int xr = xl - wx0;
        o8 [2*s  ] = (yl - wy0) * wspan + xr;
        o8 [2*s+1] = (yh - wy0) * wspan + xr;
        wlo[2*s  ] = wyl * (1.0f - fx);
        whi[2*s  ] = wyl * fx;
        wlo[2*s+1] = wyh * (1.0f - fx);
        whi[2*s+1] = wyh * fx;
    }

    __syncthreads();

    // ---- compute: each wave owns 2 channels; adjacent-pair LDS reads ----
    const float* wa = win + (wid * 2    ) * WCAP;
    const float* wb = win + (wid * 2 + 1) * WCAP;

    float acc0 = 0.0f, acc1 = 0.0f;
    #pragma unroll
    for (int j = 0; j < 8; ++j) {
        const int oj = o8[j];
        const float a_lo = wa[oj], a_hi = wa[oj + 1];
        const float b_lo = wb[oj], b_hi = wb[oj + 1];
        acc0 += wlo[j] * a_lo + whi[j] * a_hi;
        acc1 += wlo[j] * b_lo + whi[j] * b_hi;
    }

    if (lane < 49) {
        float* outp = out + (size_t)m * COUT + (size_t)(c0 + wid * 2) * NBIN + lane;
        __builtin_nontemporal_store(acc0, outp);
        __builtin_nontemporal_store(acc1, outp + NBIN);
    }
}

extern "C" void kernel_launch(void* const* d_in, const int* in_sizes, int n_in,
                              void* d_out, int out_size, void* d_ws, size_t ws_size,
                              hipStream_t stream) {
    const float* f2    = (const float*)d_in[0];
    const float* f3    = (const float*)d_in[1];
    const float* f4    = (const float*)d_in[2];
    const float* f5    = (const float*)d_in[3];
    const float* boxes = (const float*)d_in[4];
    float* outp = (float*)d_out;

    dim3 grid(NBATCH * KBOX * BPB);   // 32768 blocks: one box x 8 channels each
    dim3 block(256);
    roi_align_kernel<<<grid, block, 0, stream>>>(f2, f3, f4, f5, boxes, outp);
}